// Round 1
// baseline (223.432 us; speedup 1.0000x reference)
//
#include <hip/hip_runtime.h>
#include <stdint.h>

#define NELEM 1843200   // 16*128*30*30

// ---------------- threefry2x32 (JAX) ----------------
__device__ __forceinline__ uint32_t rotl32(uint32_t x, uint32_t r){ return (x<<r)|(x>>(32u-r)); }

__device__ __forceinline__ void tf2x32(uint32_t k0, uint32_t k1, uint32_t& x0, uint32_t& x1){
  uint32_t ks0=k0, ks1=k1, ks2=k0^k1^0x1BD11BDAu;
  x0 += ks0; x1 += ks1;
#define TFR(r) { x0 += x1; x1 = rotl32(x1,(r)); x1 ^= x0; }
  TFR(13) TFR(15) TFR(26) TFR(6)
  x0 += ks1; x1 += ks2 + 1u;
  TFR(17) TFR(29) TFR(16) TFR(24)
  x0 += ks2; x1 += ks0 + 2u;
  TFR(13) TFR(15) TFR(26) TFR(6)
  x0 += ks0; x1 += ks1 + 3u;
  TFR(17) TFR(29) TFR(16) TFR(24)
  x0 += ks1; x1 += ks2 + 4u;
  TFR(13) TFR(15) TFR(26) TFR(6)
  x0 += ks2; x1 += ks0 + 5u;
#undef TFR
}

// ---------------- MT19937 (numpy RandomState(0)) + derived threefry keys ----------------
__global__ void mt_k(uint32_t* __restrict__ rsel, uint32_t* __restrict__ keys){
  if (threadIdx.x != 0 || blockIdx.x != 0) return;
  uint32_t mt[624];
  mt[0] = 0u; // seed 0
  for (int i=1;i<624;i++) mt[i] = 1812433253u * (mt[i-1] ^ (mt[i-1] >> 30)) + (uint32_t)i;
  for (int i=0;i<624;i++){
    uint32_t y = (mt[i] & 0x80000000u) | (mt[(i+1)%624] & 0x7fffffffu);
    uint32_t v = mt[(i+397)%624] ^ (y >> 1);
    if (y & 1u) v ^= 0x9908b0dfu;
    mt[i] = v;
  }
  // legacy randint(0,64): ONE 32-bit tempered draw per call, & 63 (mask==rng, no rejection)
  for (int k=0;k<128;k++){
    uint32_t z = mt[k];
    z ^= z >> 11;
    z ^= (z << 7)  & 0x9d2c5680u;
    z ^= (z << 15) & 0xefc60000u;
    z ^= z >> 18;
    rsel[k] = z & 63u;
  }
  // partitionable (foldlike) split of key(42) = (0,42): key_i = cipher(key, hi=0, lo=i)
  uint32_t a0=0u, a1=0u; tf2x32(0u, 42u, a0, a1); keys[0]=a0; keys[1]=a1; // nk
  uint32_t b0=0u, b1=1u; tf2x32(0u, 42u, b0, b1); keys[2]=b0; keys[3]=b1; // uk
}

// ---------------- argmax of ck/0.01 + APPOINTED, per output channel ----------------
__global__ __launch_bounds__(64) void argmax_k(const float* __restrict__ ck,
    const uint32_t* __restrict__ rsel, uint32_t* __restrict__ sel){
  int o = blockIdx.x;            // 0..767
  int lane = threadIdx.x;        // 0..63
  uint32_t rb = rsel[o/6];
  bool isap = (o % 6) == 0;
  float bv = -3.4e38f; int bi = 0x7fffffff;
  for (int t = lane; t < 576; t += 64){
    float v = ck[o*576 + t] / 0.01f;
    if (isap && (uint32_t)(t/9) == rb) v += 6.0f;
    if (v > bv) { bv = v; bi = t; }   // ascending t -> first max within lane
  }
  for (int off=32; off>0; off>>=1){
    float ov = __shfl_xor(bv, off);
    int   oi = __shfl_xor(bi, off);
    if (ov > bv || (ov == bv && oi < bi)) { bv = ov; bi = oi; }
  }
  if (lane == 0) sel[o] = (uint32_t)bi;
}

// ---------------- gather-conv + LUT layer, f64 channel stats ----------------
__global__ __launch_bounds__(256) void c1_k(const float* __restrict__ inp,
    const float* __restrict__ lut, const uint32_t* __restrict__ sel,
    float* __restrict__ yraw, double* __restrict__ S1, double* __restrict__ S2){
#pragma clang fp contract(off)
  const int blk = blockIdx.x;      // b*128 + d
  const int b = blk >> 7;
  const int d = blk & 127;
  int cc[6], yy[6], xx[6];
  #pragma unroll
  for (int j=0;j<6;j++){
    uint32_t t = sel[d*6+j];
    cc[j] = (int)(t/9u); int rem = (int)(t%9u); yy[j] = rem/3; xx[j] = rem%3;
  }
  const float* w = lut + d*64;
  double l1 = 0.0, l2 = 0.0;
  for (int p = threadIdx.x; p < 900; p += 256){
    int ho = p/30, wo = p - ho*30;
    float lx[6], l1x[6];
    #pragma unroll
    for (int j=0;j<6;j++){
      float x = inp[((b*64 + cc[j])*32 + ho + yy[j])*32 + wo + xx[j]];
      lx[j]  = logf(x + 1e-7f);           // relu(x)+eps, x>=0
      l1x[j] = logf((1.0f - x) + 1e-7f);  // relu(1-x)+eps, x<1
    }
    // S_i = sum_{k=0..11, einsum order} selected logs:
    //  k=j   (j=0..5): add l1x[j] if MSB-first bit j of i is 1  (i & (32>>j))
    //  k=6+j (j=0..5): add lx[j]  if bit is 0
    float a[64];
    #pragma unroll
    for (int i=0;i<64;i++) a[i] = 0.0f;
    #pragma unroll
    for (int j=0;j<6;j++){
      const int bit = 32 >> j;
      #pragma unroll
      for (int i=0;i<64;i++) if (i & bit) a[i] += l1x[j];
    }
    #pragma unroll
    for (int j=0;j<6;j++){
      const int bit = 32 >> j;
      #pragma unroll
      for (int i=0;i<64;i++) if (!(i & bit)) a[i] += lx[j];
    }
    float y = 0.0f;
    #pragma unroll
    for (int i=0;i<64;i++){
      float t = expf(a[i]) * w[i];   // separate mul/add (contract off) like XLA
      y = y + t;
    }
    yraw[blk*900 + p] = y;
    l1 += (double)y;
    l2 += (double)y * (double)y;
  }
  #pragma unroll
  for (int off=32; off>0; off>>=1){
    l1 += __shfl_down(l1, off);
    l2 += __shfl_down(l2, off);
  }
  __shared__ double sh1[4], sh2[4];
  int wid = threadIdx.x >> 6;
  if ((threadIdx.x & 63) == 0){ sh1[wid] = l1; sh2[wid] = l2; }
  __syncthreads();
  if (threadIdx.x == 0){
    atomicAdd(&S1[d], sh1[0]+sh1[1]+sh1[2]+sh1[3]);
    atomicAdd(&S2[d], sh2[0]+sh2[1]+sh2[2]+sh2[3]);
  }
}

// ---------------- per-channel mean / biased var ----------------
__global__ void c2_k(const double* __restrict__ S1, const double* __restrict__ S2,
                     float* __restrict__ mean, float* __restrict__ var){
  int d = threadIdx.x;
  double m = S1[d] / 14400.0;
  float m32 = (float)m;
  double ey2 = S2[d] / 14400.0;
  double v = ey2 - 2.0*(double)m32*m + (double)m32*(double)m32; // E[(y-m32)^2]
  mean[d] = m32;
  var[d]  = (float)v;
}

// ---------------- XLA f32 erfinv (Giles) ----------------
__device__ __forceinline__ float erfinv_xla(float x){
#pragma clang fp contract(off)
  float w = -log1pf(-(x*x));
  float p;
  if (w < 5.0f){
    w = w - 2.5f;
    p = 2.81022636e-08f;
    p = 3.43273939e-07f  + p*w;
    p = -3.5233877e-06f  + p*w;
    p = -4.39150654e-06f + p*w;
    p = 0.00021858087f   + p*w;
    p = -0.00125372503f  + p*w;
    p = -0.00417768164f  + p*w;
    p = 0.246640727f     + p*w;
    p = 1.50140941f      + p*w;
  } else {
    w = sqrtf(w) - 3.0f;
    p = -0.000200214257f;
    p = 0.000100950558f  + p*w;
    p = 0.00134934322f   + p*w;
    p = -0.00367342844f  + p*w;
    p = 0.00573950773f   + p*w;
    p = -0.0076224613f   + p*w;
    p = 0.00943887047f   + p*w;
    p = 1.00167406f      + p*w;
    p = 2.83297682f      + p*w;
  }
  return p * x;
}

// ---------------- XLA/Eigen fast tanh f32 ----------------
__device__ __forceinline__ float fast_tanh_xla(float x){
  float ax = fabsf(x);
  float cx = fmaxf(fminf(x, 7.90531110763549805f), -7.90531110763549805f);
  float x2 = cx*cx;
  float np_ = fmaf(x2, -2.76076847742355e-16f, 2.00018790482477e-13f);
  np_ = fmaf(x2, np_, -8.60467152213735e-11f);
  np_ = fmaf(x2, np_, 5.12229709037114e-08f);
  np_ = fmaf(x2, np_, 1.48572235717979e-05f);
  np_ = fmaf(x2, np_, 6.37261928875436e-04f);
  np_ = fmaf(x2, np_, 4.89352455891786e-03f);
  float num = cx * np_;
  float dp_ = fmaf(x2, 1.19825839466702e-06f, 1.18534705686654e-04f);
  dp_ = fmaf(x2, dp_, 2.26843463243900e-03f);
  dp_ = fmaf(x2, dp_, 4.89352518554385e-03f);
  return (ax < 0.0004f) ? x : (num / dp_);
}

// ---------------- BN normalize + noise + stochastic quant ----------------
__global__ __launch_bounds__(256) void c3_k(float* __restrict__ out,
    const float* __restrict__ mean, const float* __restrict__ var,
    const uint32_t* __restrict__ keys){
#pragma clang fp contract(off)
  int i = blockIdx.x * 256 + threadIdx.x;
  if (i >= NELEM) return;
  int d = (i / 900) & 127;
  float yr = out[NELEM + i];
  float y = (yr - mean[d]) / sqrtf(var[d] + 1e-5f);

  // normal(nk): partitionable bits = o0^o1 of cipher(nk, hi=0, lo=i)
  uint32_t a0 = 0u, a1 = (uint32_t)i;
  tf2x32(keys[0], keys[1], a0, a1);
  uint32_t nb = a0 ^ a1;
  float u01 = __uint_as_float((nb >> 9) | 0x3f800000u) - 1.0f;
  const float lo = __uint_as_float(0xBF7FFFFFu);       // nextafter(-1,0) f32
  float un = u01 * 2.0f + lo;                           // (hi-lo) rounds to 2.0f
  un = fmaxf(lo, un);
  float noise = __uint_as_float(0x3FB504F3u) * erfinv_xla(un); // f32(sqrt(2))
  float xn = y + noise * 0.2f;
  out[i] = xn;

  // uniform(uk) in [0,1)
  uint32_t b0 = 0u, b1 = (uint32_t)i;
  tf2x32(keys[2], keys[3], b0, b1);
  uint32_t rb = b0 ^ b1;
  float r = __uint_as_float((rb >> 9) | 0x3f800000u) - 1.0f;

  // sigmoid via XLA logistic expansion: 0.5 + 0.5*tanh(0.5*x)
  float s = 0.5f + 0.5f * fast_tanh_xla(0.5f * xn);
  out[NELEM + i] = (s > r) ? 1.0f : 0.0f;
}

extern "C" void kernel_launch(void* const* d_in, const int* in_sizes, int n_in,
                              void* d_out, int out_size, void* d_ws, size_t ws_size,
                              hipStream_t stream) {
  (void)in_sizes; (void)n_in; (void)out_size; (void)ws_size;
  const float* inp = (const float*)d_in[0];
  const float* ck  = (const float*)d_in[1];
  const float* lut = (const float*)d_in[2];
  float* out = (float*)d_out;

  uint32_t* rsel = (uint32_t*)d_ws;                  // 128
  uint32_t* sel  = rsel + 128;                       // 768
  double*   S1   = (double*)((char*)d_ws + 4096);    // 128
  double*   S2   = S1 + 128;                         // 128
  float*    mean = (float*)(S2 + 128);               // 128
  float*    var  = mean + 128;                       // 128
  uint32_t* keys = (uint32_t*)(var + 128);           // 4

  hipMemsetAsync((char*)d_ws + 4096, 0, 2048, stream); // zero S1,S2
  hipLaunchKernelGGL(mt_k,     dim3(1),    dim3(1),   0, stream, rsel, keys);
  hipLaunchKernelGGL(argmax_k, dim3(768),  dim3(64),  0, stream, ck, rsel, sel);
  hipLaunchKernelGGL(c1_k,     dim3(2048), dim3(256), 0, stream, inp, lut, sel, out + NELEM, S1, S2);
  hipLaunchKernelGGL(c2_k,     dim3(1),    dim3(128), 0, stream, S1, S2, mean, var);
  hipLaunchKernelGGL(c3_k,     dim3(7200), dim3(256), 0, stream, out, mean, var, keys);
}

// Round 2
// 103.226 us; speedup vs baseline: 2.1645x; 2.1645x over previous
//
#include <hip/hip_runtime.h>
#include <stdint.h>

#define NELEM 1843200   // 16*128*30*30

// ================= compile-time MT19937 (numpy RandomState(0)) =================
struct RselT { uint32_t v[128]; };
constexpr RselT compute_rsel(){
  uint32_t mt[624] = {};
  mt[0] = 0u;
  for (int i=1;i<624;i++) mt[i] = 1812433253u * (mt[i-1] ^ (mt[i-1] >> 30)) + (uint32_t)i;
  for (int i=0;i<624;i++){
    uint32_t y = (mt[i] & 0x80000000u) | (mt[(i+1)%624] & 0x7fffffffu);
    uint32_t v = mt[(i+397)%624] ^ (y >> 1);
    if (y & 1u) v ^= 0x9908b0dfu;
    mt[i] = v;
  }
  RselT r{};
  for (int k=0;k<128;k++){
    uint32_t z = mt[k];
    z ^= z >> 11;
    z ^= (z << 7)  & 0x9d2c5680u;
    z ^= (z << 15) & 0xefc60000u;
    z ^= z >> 18;
    r.v[k] = z & 63u;   // legacy randint(0,64): one tempered draw, mask 63
  }
  return r;
}
__device__ __constant__ RselT RSEL = compute_rsel();

// ================= threefry2x32 =================
__device__ __forceinline__ uint32_t rotl32(uint32_t x, uint32_t r){ return (x<<r)|(x>>(32u-r)); }

__device__ __forceinline__ void tf2x32(uint32_t k0, uint32_t k1, uint32_t& x0, uint32_t& x1){
  uint32_t ks0=k0, ks1=k1, ks2=k0^k1^0x1BD11BDAu;
  x0 += ks0; x1 += ks1;
#define TFR(r) { x0 += x1; x1 = rotl32(x1,(r)); x1 ^= x0; }
  TFR(13) TFR(15) TFR(26) TFR(6)
  x0 += ks1; x1 += ks2 + 1u;
  TFR(17) TFR(29) TFR(16) TFR(24)
  x0 += ks2; x1 += ks0 + 2u;
  TFR(13) TFR(15) TFR(26) TFR(6)
  x0 += ks0; x1 += ks1 + 3u;
  TFR(17) TFR(29) TFR(16) TFR(24)
  x0 += ks1; x1 += ks2 + 4u;
  TFR(13) TFR(15) TFR(26) TFR(6)
  x0 += ks2; x1 += ks0 + 5u;
#undef TFR
}

// compile-time threefry for the key-split of key(42): key_i = cipher((0,42), (0,i))
struct K2 { uint32_t a, b; };
constexpr uint32_t rotl_c(uint32_t x, int r){ return (x<<r)|(x>>(32-r)); }
constexpr K2 tf_c(uint32_t k0, uint32_t k1, uint32_t x0, uint32_t x1){
  uint32_t ks0=k0, ks1=k1, ks2=k0^k1^0x1BD11BDAu;
  x0 += ks0; x1 += ks1;
#define TFC(r) { x0 += x1; x1 = rotl_c(x1,(r)); x1 ^= x0; }
  TFC(13) TFC(15) TFC(26) TFC(6)
  x0 += ks1; x1 += ks2 + 1u;
  TFC(17) TFC(29) TFC(16) TFC(24)
  x0 += ks2; x1 += ks0 + 2u;
  TFC(13) TFC(15) TFC(26) TFC(6)
  x0 += ks0; x1 += ks1 + 3u;
  TFC(17) TFC(29) TFC(16) TFC(24)
  x0 += ks1; x1 += ks2 + 4u;
  TFC(13) TFC(15) TFC(26) TFC(6)
  x0 += ks2; x1 += ks0 + 5u;
#undef TFC
  return K2{x0, x1};
}
constexpr K2 NK = tf_c(0u, 42u, 0u, 0u);   // noise key
constexpr K2 UK = tf_c(0u, 42u, 0u, 1u);   // uniform key

// ================= argmax of ck/0.01 + APPOINTED, per output channel =================
__global__ __launch_bounds__(64) void argmax_k(const float* __restrict__ ck,
    uint32_t* __restrict__ sel){
  int o = blockIdx.x;            // 0..767
  int lane = threadIdx.x;        // 0..63
  uint32_t rb = RSEL.v[o/6];
  bool isap = (o % 6) == 0;
  float bv = -3.4e38f; int bi = 0x7fffffff;
  for (int t = lane; t < 576; t += 64){
    float v = ck[o*576 + t] / 0.01f;
    if (isap && (uint32_t)(t/9) == rb) v += 6.0f;
    if (v > bv) { bv = v; bi = t; }   // ascending t -> first max within lane
  }
  for (int off=32; off>0; off>>=1){
    float ov = __shfl_xor(bv, off);
    int   oi = __shfl_xor(bi, off);
    if (ov > bv || (ov == bv && oi < bi)) { bv = ov; bi = oi; }
  }
  if (lane == 0) sel[o] = (uint32_t)bi;
}

// ================= gather-conv + LUT layer, f64 channel stats =================
__global__ __launch_bounds__(256) void c1_k(const float* __restrict__ inp,
    const float* __restrict__ lut, const uint32_t* __restrict__ sel,
    float* __restrict__ yraw, double* __restrict__ S1, double* __restrict__ S2){
#pragma clang fp contract(off)
  const int blk = blockIdx.x;      // b*128 + d
  const int b = blk >> 7;
  const int d = blk & 127;
  int cc[6], yy[6], xx[6];
  #pragma unroll
  for (int j=0;j<6;j++){
    uint32_t t = sel[d*6+j];
    cc[j] = (int)(t/9u); int rem = (int)(t%9u); yy[j] = rem/3; xx[j] = rem%3;
  }
  const float* w = lut + d*64;
  double l1 = 0.0, l2 = 0.0;
  for (int p = threadIdx.x; p < 900; p += 256){
    int ho = p/30, wo = p - ho*30;
    float lx[6], l1x[6];
    #pragma unroll
    for (int j=0;j<6;j++){
      float x = inp[((b*64 + cc[j])*32 + ho + yy[j])*32 + wo + xx[j]];
      lx[j]  = logf(x + 1e-7f);           // relu(x)+eps, x>=0
      l1x[j] = logf((1.0f - x) + 1e-7f);  // relu(1-x)+eps, x<1
    }
    float a[64];
    #pragma unroll
    for (int i=0;i<64;i++) a[i] = 0.0f;
    #pragma unroll
    for (int j=0;j<6;j++){
      const int bit = 32 >> j;
      #pragma unroll
      for (int i=0;i<64;i++) if (i & bit) a[i] += l1x[j];
    }
    #pragma unroll
    for (int j=0;j<6;j++){
      const int bit = 32 >> j;
      #pragma unroll
      for (int i=0;i<64;i++) if (!(i & bit)) a[i] += lx[j];
    }
    float y = 0.0f;
    #pragma unroll
    for (int i=0;i<64;i++){
      float t = expf(a[i]) * w[i];   // separate mul/add (contract off) like XLA
      y = y + t;
    }
    yraw[blk*900 + p] = y;
    l1 += (double)y;
    l2 += (double)y * (double)y;
  }
  #pragma unroll
  for (int off=32; off>0; off>>=1){
    l1 += __shfl_down(l1, off);
    l2 += __shfl_down(l2, off);
  }
  __shared__ double sh1[4], sh2[4];
  int wid = threadIdx.x >> 6;
  if ((threadIdx.x & 63) == 0){ sh1[wid] = l1; sh2[wid] = l2; }
  __syncthreads();
  if (threadIdx.x == 0){
    atomicAdd(&S1[d], sh1[0]+sh1[1]+sh1[2]+sh1[3]);
    atomicAdd(&S2[d], sh2[0]+sh2[1]+sh2[2]+sh2[3]);
  }
}

// ================= XLA f32 erfinv (Giles) =================
__device__ __forceinline__ float erfinv_xla(float x){
#pragma clang fp contract(off)
  float w = -log1pf(-(x*x));
  float p;
  if (w < 5.0f){
    w = w - 2.5f;
    p = 2.81022636e-08f;
    p = 3.43273939e-07f  + p*w;
    p = -3.5233877e-06f  + p*w;
    p = -4.39150654e-06f + p*w;
    p = 0.00021858087f   + p*w;
    p = -0.00125372503f  + p*w;
    p = -0.00417768164f  + p*w;
    p = 0.246640727f     + p*w;
    p = 1.50140941f      + p*w;
  } else {
    w = sqrtf(w) - 3.0f;
    p = -0.000200214257f;
    p = 0.000100950558f  + p*w;
    p = 0.00134934322f   + p*w;
    p = -0.00367342844f  + p*w;
    p = 0.00573950773f   + p*w;
    p = -0.0076224613f   + p*w;
    p = 0.00943887047f   + p*w;
    p = 1.00167406f      + p*w;
    p = 2.83297682f      + p*w;
  }
  return p * x;
}

// ================= XLA/Eigen fast tanh f32 =================
__device__ __forceinline__ float fast_tanh_xla(float x){
  float ax = fabsf(x);
  float cx = fmaxf(fminf(x, 7.90531110763549805f), -7.90531110763549805f);
  float x2 = cx*cx;
  float np_ = fmaf(x2, -2.76076847742355e-16f, 2.00018790482477e-13f);
  np_ = fmaf(x2, np_, -8.60467152213735e-11f);
  np_ = fmaf(x2, np_, 5.12229709037114e-08f);
  np_ = fmaf(x2, np_, 1.48572235717979e-05f);
  np_ = fmaf(x2, np_, 6.37261928875436e-04f);
  np_ = fmaf(x2, np_, 4.89352455891786e-03f);
  float num = cx * np_;
  float dp_ = fmaf(x2, 1.19825839466702e-06f, 1.18534705686654e-04f);
  dp_ = fmaf(x2, dp_, 2.26843463243900e-03f);
  dp_ = fmaf(x2, dp_, 4.89352518554385e-03f);
  return (ax < 0.0004f) ? x : (num / dp_);
}

// ================= BN finalize + normalize + noise + stochastic quant =================
__global__ __launch_bounds__(256) void c3_k(float* __restrict__ out,
    const double* __restrict__ S1, const double* __restrict__ S2){
#pragma clang fp contract(off)
  int i = blockIdx.x * 256 + threadIdx.x;
  if (i >= NELEM) return;
  int d = (i / 900) & 127;

  // fused c2: per-channel mean / biased var (identical arithmetic to the old c2_k)
  double m = S1[d] / 14400.0;
  float m32 = (float)m;
  double ey2 = S2[d] / 14400.0;
  double v = ey2 - 2.0*(double)m32*m + (double)m32*(double)m32; // E[(y-m32)^2]
  float var32 = (float)v;

  float yr = out[NELEM + i];
  float y = (yr - m32) / sqrtf(var32 + 1e-5f);

  // normal(nk): partitionable bits = o0^o1 of cipher(nk, hi=0, lo=i)
  uint32_t a0 = NK.a, a1v = NK.b;
  { uint32_t x0 = 0u, x1 = (uint32_t)i; tf2x32(a0, a1v, x0, x1);
    uint32_t nb = x0 ^ x1;
    float u01 = __uint_as_float((nb >> 9) | 0x3f800000u) - 1.0f;
    const float lo = __uint_as_float(0xBF7FFFFFu);       // nextafter(-1,0) f32
    float un = u01 * 2.0f + lo;
    un = fmaxf(lo, un);
    float noise = __uint_as_float(0x3FB504F3u) * erfinv_xla(un); // f32(sqrt(2))
    y = y + noise * 0.2f;
  }
  out[i] = y;

  // uniform(uk) in [0,1)
  uint32_t x0 = 0u, x1 = (uint32_t)i;
  tf2x32(UK.a, UK.b, x0, x1);
  uint32_t rb = x0 ^ x1;
  float r = __uint_as_float((rb >> 9) | 0x3f800000u) - 1.0f;

  // sigmoid via XLA logistic expansion: 0.5 + 0.5*tanh(0.5*x)
  float s = 0.5f + 0.5f * fast_tanh_xla(0.5f * y);
  out[NELEM + i] = (s > r) ? 1.0f : 0.0f;
}

extern "C" void kernel_launch(void* const* d_in, const int* in_sizes, int n_in,
                              void* d_out, int out_size, void* d_ws, size_t ws_size,
                              hipStream_t stream) {
  (void)in_sizes; (void)n_in; (void)out_size; (void)ws_size;
  const float* inp = (const float*)d_in[0];
  const float* ck  = (const float*)d_in[1];
  const float* lut = (const float*)d_in[2];
  float* out = (float*)d_out;

  uint32_t* sel = (uint32_t*)d_ws;                   // 768
  double*   S1  = (double*)((char*)d_ws + 4096);     // 128
  double*   S2  = S1 + 128;                          // 128

  hipMemsetAsync((char*)d_ws + 4096, 0, 2048, stream); // zero S1,S2
  hipLaunchKernelGGL(argmax_k, dim3(768),  dim3(64),  0, stream, ck, sel);
  hipLaunchKernelGGL(c1_k,     dim3(2048), dim3(256), 0, stream, inp, lut, sel, out + NELEM, S1, S2);
  hipLaunchKernelGGL(c3_k,     dim3(7200), dim3(256), 0, stream, out, S1, S2);
}

// Round 3
// 99.457 us; speedup vs baseline: 2.2465x; 1.0379x over previous
//
#include <hip/hip_runtime.h>
#include <stdint.h>

#define NELEM 1843200   // 16*128*30*30
#define NPIX  1048576   // 16*64*32*32

typedef float v2f __attribute__((ext_vector_type(2)));

// ================= compile-time MT19937 (numpy RandomState(0)) =================
struct RselT { uint32_t v[128]; };
constexpr RselT compute_rsel(){
  uint32_t mt[624] = {};
  mt[0] = 0u;
  for (int i=1;i<624;i++) mt[i] = 1812433253u * (mt[i-1] ^ (mt[i-1] >> 30)) + (uint32_t)i;
  for (int i=0;i<624;i++){
    uint32_t y = (mt[i] & 0x80000000u) | (mt[(i+1)%624] & 0x7fffffffu);
    uint32_t v = mt[(i+397)%624] ^ (y >> 1);
    if (y & 1u) v ^= 0x9908b0dfu;
    mt[i] = v;
  }
  RselT r{};
  for (int k=0;k<128;k++){
    uint32_t z = mt[k];
    z ^= z >> 11;
    z ^= (z << 7)  & 0x9d2c5680u;
    z ^= (z << 15) & 0xefc60000u;
    z ^= z >> 18;
    r.v[k] = z & 63u;   // legacy randint(0,64): one tempered draw, mask 63
  }
  return r;
}
__device__ __constant__ RselT RSEL = compute_rsel();

// ================= threefry2x32 =================
__device__ __forceinline__ uint32_t rotl32(uint32_t x, uint32_t r){ return (x<<r)|(x>>(32u-r)); }

__device__ __forceinline__ void tf2x32(uint32_t k0, uint32_t k1, uint32_t& x0, uint32_t& x1){
  uint32_t ks0=k0, ks1=k1, ks2=k0^k1^0x1BD11BDAu;
  x0 += ks0; x1 += ks1;
#define TFR(r) { x0 += x1; x1 = rotl32(x1,(r)); x1 ^= x0; }
  TFR(13) TFR(15) TFR(26) TFR(6)
  x0 += ks1; x1 += ks2 + 1u;
  TFR(17) TFR(29) TFR(16) TFR(24)
  x0 += ks2; x1 += ks0 + 2u;
  TFR(13) TFR(15) TFR(26) TFR(6)
  x0 += ks0; x1 += ks1 + 3u;
  TFR(17) TFR(29) TFR(16) TFR(24)
  x0 += ks1; x1 += ks2 + 4u;
  TFR(13) TFR(15) TFR(26) TFR(6)
  x0 += ks2; x1 += ks0 + 5u;
#undef TFR
}

// compile-time threefry for the key-split of key(42)
struct K2 { uint32_t a, b; };
constexpr uint32_t rotl_c(uint32_t x, int r){ return (x<<r)|(x>>(32-r)); }
constexpr K2 tf_c(uint32_t k0, uint32_t k1, uint32_t x0, uint32_t x1){
  uint32_t ks0=k0, ks1=k1, ks2=k0^k1^0x1BD11BDAu;
  x0 += ks0; x1 += ks1;
#define TFC(r) { x0 += x1; x1 = rotl_c(x1,(r)); x1 ^= x0; }
  TFC(13) TFC(15) TFC(26) TFC(6)
  x0 += ks1; x1 += ks2 + 1u;
  TFC(17) TFC(29) TFC(16) TFC(24)
  x0 += ks2; x1 += ks0 + 2u;
  TFC(13) TFC(15) TFC(26) TFC(6)
  x0 += ks0; x1 += ks1 + 3u;
  TFC(17) TFC(29) TFC(16) TFC(24)
  x0 += ks1; x1 += ks2 + 4u;
  TFC(13) TFC(15) TFC(26) TFC(6)
  x0 += ks2; x1 += ks0 + 5u;
#undef TFC
  return K2{x0, x1};
}
constexpr K2 NK = tf_c(0u, 42u, 0u, 0u);   // noise key
constexpr K2 UK = tf_c(0u, 42u, 0u, 1u);   // uniform key

// ================= argmax of ck/0.01 + APPOINTED =================
__global__ __launch_bounds__(64) void argmax_k(const float* __restrict__ ck,
    uint32_t* __restrict__ sel){
  int o = blockIdx.x;            // 0..767
  int lane = threadIdx.x;        // 0..63
  uint32_t rb = RSEL.v[o/6];
  bool isap = (o % 6) == 0;
  float bv = -3.4e38f; int bi = 0x7fffffff;
  for (int t = lane; t < 576; t += 64){
    float v = ck[o*576 + t] / 0.01f;
    if (isap && (uint32_t)(t/9) == rb) v += 6.0f;
    if (v > bv) { bv = v; bi = t; }
  }
  for (int off=32; off>0; off>>=1){
    float ov = __shfl_xor(bv, off);
    int   oi = __shfl_xor(bi, off);
    if (ov > bv || (ov == bv && oi < bi)) { bv = ov; bi = oi; }
  }
  if (lane == 0) sel[o] = (uint32_t)bi;
}

// ================= log precompute: lg[pix] = (log(x+eps), log(1-x+eps)) ===========
__global__ __launch_bounds__(256) void pre_k(const float* __restrict__ inp,
                                             v2f* __restrict__ lg){
  int i = blockIdx.x * 256 + threadIdx.x;   // exactly NPIX
  float x = inp[i];
  v2f r;
  r[0] = logf(x + 1e-7f);            // relu(x)+eps, x>=0
  r[1] = logf((1.0f - x) + 1e-7f);   // relu(1-x)+eps, x<1
  lg[i] = r;
}

// ================= gather-conv + LUT layer, f64 channel stats =================
// PRE=1: logs gathered from lg table (bit-identical to inline logf).
template<int PRE>
__global__ __launch_bounds__(256) void c1_k(const float* __restrict__ inp,
    const v2f* __restrict__ lg,
    const float* __restrict__ lut, const uint32_t* __restrict__ sel,
    float* __restrict__ yraw, double* __restrict__ S1, double* __restrict__ S2){
#pragma clang fp contract(off)
  const int blk = blockIdx.x;      // b*128 + d
  const int b = blk >> 7;
  const int d = blk & 127;
  int off6[6];
  #pragma unroll
  for (int j=0;j<6;j++){
    uint32_t t = sel[d*6+j];
    int cc = (int)(t/9u); int rem = (int)(t%9u);
    off6[j] = cc*1024 + (rem/3)*32 + (rem%3);
  }
  const int pbase = b*65536;
  const float* w = lut + d*64;
  double acc1 = 0.0, acc2 = 0.0;
  for (int p = threadIdx.x; p < 900; p += 256){
    int ho = p/30, wo = p - ho*30;
    int pix = pbase + ho*32 + wo;
    float lx[6], l1x[6];
    #pragma unroll
    for (int j=0;j<6;j++){
      if (PRE){
        v2f v = lg[pix + off6[j]];
        lx[j] = v[0]; l1x[j] = v[1];
      } else {
        float x = inp[pix + off6[j]];
        lx[j]  = logf(x + 1e-7f);
        l1x[j] = logf((1.0f - x) + 1e-7f);
      }
    }
    // phase 1: subset-sum DP over l1x (set bits, ascending j) — association-exact:
    // chain for mask m ends with its lowest-value set bit (largest j), so
    // S[m] = S[m & (m-1)] + l1x[5 - ctz(m)].
    float S[64];
    S[0] = 0.0f;
    #pragma unroll
    for (int m=1;m<64;m++) S[m] = S[m & (m-1)] + l1x[5 - __builtin_ctz((unsigned)m)];
    // phase 2: add lx[j] for unset bits, ascending j; packed over (2k, 2k+1)
    v2f a2[32];
    #pragma unroll
    for (int k=0;k<32;k++){ a2[k][0] = S[2*k]; a2[k][1] = S[2*k+1]; }
    #pragma unroll
    for (int j=0;j<5;j++){
      const int bit = 32 >> j;
      #pragma unroll
      for (int k=0;k<32;k++){
        if (!((2*k) & bit)){ v2f ad; ad[0] = lx[j]; ad[1] = lx[j]; a2[k] = a2[k] + ad; }
      }
    }
    #pragma unroll
    for (int k=0;k<32;k++){ v2f ad; ad[0] = lx[5]; ad[1] = 0.0f; a2[k] = a2[k] + ad; } // +0 exact
    // exp, packed mul by w, strictly sequential i-ascending sum (XLA order)
    float y = 0.0f;
    #pragma unroll
    for (int k=0;k<32;k++){
      v2f e; e[0] = expf(a2[k][0]); e[1] = expf(a2[k][1]);
      v2f wv; wv[0] = w[2*k]; wv[1] = w[2*k+1];
      v2f t = e * wv;
      y = y + t[0];
      y = y + t[1];
    }
    yraw[blk*900 + p] = y;
    acc1 += (double)y;
    acc2 += (double)y * (double)y;
  }
  #pragma unroll
  for (int off=32; off>0; off>>=1){
    acc1 += __shfl_down(acc1, off);
    acc2 += __shfl_down(acc2, off);
  }
  __shared__ double sh1[4], sh2[4];
  int wid = threadIdx.x >> 6;
  if ((threadIdx.x & 63) == 0){ sh1[wid] = acc1; sh2[wid] = acc2; }
  __syncthreads();
  if (threadIdx.x == 0){
    atomicAdd(&S1[d], sh1[0]+sh1[1]+sh1[2]+sh1[3]);
    atomicAdd(&S2[d], sh2[0]+sh2[1]+sh2[2]+sh2[3]);
  }
}

// ================= XLA f32 erfinv (Giles) =================
__device__ __forceinline__ float erfinv_xla(float x){
#pragma clang fp contract(off)
  float w = -log1pf(-(x*x));
  float p;
  if (w < 5.0f){
    w = w - 2.5f;
    p = 2.81022636e-08f;
    p = 3.43273939e-07f  + p*w;
    p = -3.5233877e-06f  + p*w;
    p = -4.39150654e-06f + p*w;
    p = 0.00021858087f   + p*w;
    p = -0.00125372503f  + p*w;
    p = -0.00417768164f  + p*w;
    p = 0.246640727f     + p*w;
    p = 1.50140941f      + p*w;
  } else {
    w = sqrtf(w) - 3.0f;
    p = -0.000200214257f;
    p = 0.000100950558f  + p*w;
    p = 0.00134934322f   + p*w;
    p = -0.00367342844f  + p*w;
    p = 0.00573950773f   + p*w;
    p = -0.0076224613f   + p*w;
    p = 0.00943887047f   + p*w;
    p = 1.00167406f      + p*w;
    p = 2.83297682f      + p*w;
  }
  return p * x;
}

// ================= XLA/Eigen fast tanh f32 =================
__device__ __forceinline__ float fast_tanh_xla(float x){
  float ax = fabsf(x);
  float cx = fmaxf(fminf(x, 7.90531110763549805f), -7.90531110763549805f);
  float x2 = cx*cx;
  float np_ = fmaf(x2, -2.76076847742355e-16f, 2.00018790482477e-13f);
  np_ = fmaf(x2, np_, -8.60467152213735e-11f);
  np_ = fmaf(x2, np_, 5.12229709037114e-08f);
  np_ = fmaf(x2, np_, 1.48572235717979e-05f);
  np_ = fmaf(x2, np_, 6.37261928875436e-04f);
  np_ = fmaf(x2, np_, 4.89352455891786e-03f);
  float num = cx * np_;
  float dp_ = fmaf(x2, 1.19825839466702e-06f, 1.18534705686654e-04f);
  dp_ = fmaf(x2, dp_, 2.26843463243900e-03f);
  dp_ = fmaf(x2, dp_, 4.89352518554385e-03f);
  return (ax < 0.0004f) ? x : (num / dp_);
}

// ================= BN finalize + normalize + noise + stochastic quant =================
__global__ __launch_bounds__(256) void c3_k(float* __restrict__ out,
    const double* __restrict__ S1, const double* __restrict__ S2){
#pragma clang fp contract(off)
  int i = blockIdx.x * 256 + threadIdx.x;
  if (i >= NELEM) return;
  int d = (i / 900) & 127;

  double m = S1[d] / 14400.0;
  float m32 = (float)m;
  double ey2 = S2[d] / 14400.0;
  double v = ey2 - 2.0*(double)m32*m + (double)m32*(double)m32;
  float var32 = (float)v;

  float yr = out[NELEM + i];
  float y = (yr - m32) / sqrtf(var32 + 1e-5f);

  { uint32_t x0 = 0u, x1 = (uint32_t)i; tf2x32(NK.a, NK.b, x0, x1);
    uint32_t nb = x0 ^ x1;
    float u01 = __uint_as_float((nb >> 9) | 0x3f800000u) - 1.0f;
    const float lo = __uint_as_float(0xBF7FFFFFu);
    float un = u01 * 2.0f + lo;
    un = fmaxf(lo, un);
    float noise = __uint_as_float(0x3FB504F3u) * erfinv_xla(un);
    y = y + noise * 0.2f;
  }
  out[i] = y;

  uint32_t x0 = 0u, x1 = (uint32_t)i;
  tf2x32(UK.a, UK.b, x0, x1);
  uint32_t rb = x0 ^ x1;
  float r = __uint_as_float((rb >> 9) | 0x3f800000u) - 1.0f;

  float s = 0.5f + 0.5f * fast_tanh_xla(0.5f * y);
  out[NELEM + i] = (s > r) ? 1.0f : 0.0f;
}

extern "C" void kernel_launch(void* const* d_in, const int* in_sizes, int n_in,
                              void* d_out, int out_size, void* d_ws, size_t ws_size,
                              hipStream_t stream) {
  (void)in_sizes; (void)n_in; (void)out_size;
  const float* inp = (const float*)d_in[0];
  const float* ck  = (const float*)d_in[1];
  const float* lut = (const float*)d_in[2];
  float* out = (float*)d_out;

  uint32_t* sel = (uint32_t*)d_ws;                   // 768 u32
  double*   S1  = (double*)((char*)d_ws + 4096);     // 128
  double*   S2  = S1 + 128;                          // 128
  v2f*      lg  = (v2f*)((char*)d_ws + 8192);        // NPIX float2 = 8 MiB

  const size_t ws_need = 8192 + (size_t)NPIX * 8;

  hipMemsetAsync((char*)d_ws + 4096, 0, 2048, stream); // zero S1,S2
  hipLaunchKernelGGL(argmax_k, dim3(768),  dim3(64),  0, stream, ck, sel);
  if (ws_size >= ws_need){
    hipLaunchKernelGGL(pre_k,   dim3(NPIX/256), dim3(256), 0, stream, inp, lg);
    hipLaunchKernelGGL(c1_k<1>, dim3(2048),     dim3(256), 0, stream, inp, lg, lut, sel, out + NELEM, S1, S2);
  } else {
    hipLaunchKernelGGL(c1_k<0>, dim3(2048),     dim3(256), 0, stream, inp, lg, lut, sel, out + NELEM, S1, S2);
  }
  hipLaunchKernelGGL(c3_k, dim3(7200), dim3(256), 0, stream, out, S1, S2);
}

// Round 4
// 78.643 us; speedup vs baseline: 2.8411x; 1.2647x over previous
//
#include <hip/hip_runtime.h>
#include <stdint.h>

#define NELEM 1843200   // 16*128*30*30
#define NPIX  1048576   // 16*64*32*32

typedef float v2f __attribute__((ext_vector_type(2)));

// ================= compile-time MT19937 (numpy RandomState(0)) =================
struct RselT { uint32_t v[128]; };
constexpr RselT compute_rsel(){
  uint32_t mt[624] = {};
  mt[0] = 0u;
  for (int i=1;i<624;i++) mt[i] = 1812433253u * (mt[i-1] ^ (mt[i-1] >> 30)) + (uint32_t)i;
  for (int i=0;i<624;i++){
    uint32_t y = (mt[i] & 0x80000000u) | (mt[(i+1)%624] & 0x7fffffffu);
    uint32_t v = mt[(i+397)%624] ^ (y >> 1);
    if (y & 1u) v ^= 0x9908b0dfu;
    mt[i] = v;
  }
  RselT r{};
  for (int k=0;k<128;k++){
    uint32_t z = mt[k];
    z ^= z >> 11;
    z ^= (z << 7)  & 0x9d2c5680u;
    z ^= (z << 15) & 0xefc60000u;
    z ^= z >> 18;
    r.v[k] = z & 63u;   // legacy randint(0,64): one tempered draw, mask 63
  }
  return r;
}
__device__ __constant__ RselT RSEL = compute_rsel();

// ================= threefry2x32 =================
__device__ __forceinline__ uint32_t rotl32(uint32_t x, uint32_t r){ return (x<<r)|(x>>(32u-r)); }

__device__ __forceinline__ void tf2x32(uint32_t k0, uint32_t k1, uint32_t& x0, uint32_t& x1){
  uint32_t ks0=k0, ks1=k1, ks2=k0^k1^0x1BD11BDAu;
  x0 += ks0; x1 += ks1;
#define TFR(r) { x0 += x1; x1 = rotl32(x1,(r)); x1 ^= x0; }
  TFR(13) TFR(15) TFR(26) TFR(6)
  x0 += ks1; x1 += ks2 + 1u;
  TFR(17) TFR(29) TFR(16) TFR(24)
  x0 += ks2; x1 += ks0 + 2u;
  TFR(13) TFR(15) TFR(26) TFR(6)
  x0 += ks0; x1 += ks1 + 3u;
  TFR(17) TFR(29) TFR(16) TFR(24)
  x0 += ks1; x1 += ks2 + 4u;
  TFR(13) TFR(15) TFR(26) TFR(6)
  x0 += ks2; x1 += ks0 + 5u;
#undef TFR
}

// compile-time threefry for the key-split of key(42)
struct K2 { uint32_t a, b; };
constexpr uint32_t rotl_c(uint32_t x, int r){ return (x<<r)|(x>>(32-r)); }
constexpr K2 tf_c(uint32_t k0, uint32_t k1, uint32_t x0, uint32_t x1){
  uint32_t ks0=k0, ks1=k1, ks2=k0^k1^0x1BD11BDAu;
  x0 += ks0; x1 += ks1;
#define TFC(r) { x0 += x1; x1 = rotl_c(x1,(r)); x1 ^= x0; }
  TFC(13) TFC(15) TFC(26) TFC(6)
  x0 += ks1; x1 += ks2 + 1u;
  TFC(17) TFC(29) TFC(16) TFC(24)
  x0 += ks2; x1 += ks0 + 2u;
  TFC(13) TFC(15) TFC(26) TFC(6)
  x0 += ks0; x1 += ks1 + 3u;
  TFC(17) TFC(29) TFC(16) TFC(24)
  x0 += ks1; x1 += ks2 + 4u;
  TFC(13) TFC(15) TFC(26) TFC(6)
  x0 += ks2; x1 += ks0 + 5u;
#undef TFC
  return K2{x0, x1};
}
constexpr K2 NK = tf_c(0u, 42u, 0u, 0u);   // noise key
constexpr K2 UK = tf_c(0u, 42u, 0u, 1u);   // uniform key

// raw v_exp_f32 (exp2). Argument guaranteed in [-0.51, 0.51].
__device__ __forceinline__ float exp2_raw(float x){
#if __has_builtin(__builtin_amdgcn_exp2f)
  return __builtin_amdgcn_exp2f(x);
#else
  float r; asm("v_exp_f32 %0, %1" : "=v"(r) : "v"(x)); return r;
#endif
}

// ================= argmax of ck/0.01 + APPOINTED (+ zero S1/S2 in block 0) =====
__global__ __launch_bounds__(64) void argmax_k(const float* __restrict__ ck,
    uint32_t* __restrict__ sel, double* __restrict__ Sz){
  int o = blockIdx.x;            // 0..767
  int lane = threadIdx.x;        // 0..63
  if (o == 0){
    #pragma unroll
    for (int q=0;q<4;q++) Sz[lane*4+q] = 0.0;   // 256 doubles = S1(128)+S2(128)
  }
  uint32_t rb = RSEL.v[o/6];
  bool isap = (o % 6) == 0;
  float bv = -3.4e38f; int bi = 0x7fffffff;
  for (int t = lane; t < 576; t += 64){
    float v = ck[o*576 + t] / 0.01f;
    if (isap && (uint32_t)(t/9) == rb) v += 6.0f;
    if (v > bv) { bv = v; bi = t; }
  }
  for (int off=32; off>0; off>>=1){
    float ov = __shfl_xor(bv, off);
    int   oi = __shfl_xor(bi, off);
    if (ov > bv || (ov == bv && oi < bi)) { bv = ov; bi = oi; }
  }
  if (lane == 0) sel[o] = (uint32_t)bi;
}

// ================= log precompute: lg[pix] = (log(x+eps), log(1-x+eps)) ===========
__global__ __launch_bounds__(256) void pre_k(const float* __restrict__ inp,
                                             v2f* __restrict__ lg){
  int i = blockIdx.x * 256 + threadIdx.x;   // exactly NPIX
  float x = inp[i];
  v2f r;
  r[0] = logf(x + 1e-7f);            // relu(x)+eps, x>=0
  r[1] = logf((1.0f - x) + 1e-7f);   // relu(1-x)+eps, x<1
  lg[i] = r;
}

// ================= gather-conv + LUT layer, f64 channel stats =================
template<int PRE>
__global__ __launch_bounds__(256) void c1_k(const float* __restrict__ inp,
    const v2f* __restrict__ lg,
    const float* __restrict__ lut, const uint32_t* __restrict__ sel,
    float* __restrict__ yraw, double* __restrict__ S1, double* __restrict__ S2){
#pragma clang fp contract(off)
  const int blk = blockIdx.x;      // b*128 + d
  const int b = blk >> 7;
  const int d = blk & 127;
  int off6[6];
  #pragma unroll
  for (int j=0;j<6;j++){
    uint32_t t = sel[d*6+j];
    int cc = (int)(t/9u); int rem = (int)(t%9u);
    off6[j] = cc*1024 + (rem/3)*32 + (rem%3);
  }
  const int pbase = b*65536;
  const v2f* wv2 = (const v2f*)(lut + d*64);
  // exp lowering constants (LLVM AMDGPU lowerFEXP, f32 path)
  const v2f C2  = (v2f){0x1.715476p+0f, 0x1.715476p+0f};
  const v2f CC2 = (v2f){0x1.4ae0bep-26f, 0x1.4ae0bep-26f};
  double acc1 = 0.0, acc2 = 0.0;
  for (int p = threadIdx.x; p < 900; p += 256){
    int ho = p/30, wo = p - ho*30;
    int pix = pbase + ho*32 + wo;
    float lx[6], l1x[6];
    #pragma unroll
    for (int j=0;j<6;j++){
      if (PRE){
        v2f v = lg[pix + off6[j]];
        lx[j] = v[0]; l1x[j] = v[1];
      } else {
        float x = inp[pix + off6[j]];
        lx[j]  = logf(x + 1e-7f);
        l1x[j] = logf((1.0f - x) + 1e-7f);
      }
    }
    // phase 1: subset-sum DP over l1x (set bits, ascending j) — association-exact
    float S[64];
    S[0] = 0.0f;
    #pragma unroll
    for (int m=1;m<64;m++) S[m] = S[m & (m-1)] + l1x[5 - __builtin_ctz((unsigned)m)];
    // phase 2: add lx[j] for unset bits, ascending j; packed over (2k, 2k+1)
    v2f a2[32];
    #pragma unroll
    for (int k=0;k<32;k++){ a2[k][0] = S[2*k]; a2[k][1] = S[2*k+1]; }
    #pragma unroll
    for (int j=0;j<5;j++){
      const int bit = 32 >> j;
      #pragma unroll
      for (int k=0;k<32;k++){
        if (!((2*k) & bit)){ v2f ad; ad[0] = lx[j]; ad[1] = lx[j]; a2[k] = a2[k] + ad; }
      }
    }
    #pragma unroll
    for (int k=0;k<32;k++){ v2f ad; ad[0] = lx[5]; ad[1] = 0.0f; a2[k] = a2[k] + ad; } // +0 exact
    // exp (hand-inlined lowerFEXP minus unreachable range selects:
    //  a in [-96.71, 7.2e-7] strictly inside (-0x1.9d1da0p+6, 0x1.62e430p+6)),
    // then packed mul by w, strictly sequential i-ascending sum (XLA order)
    float y = 0.0f;
    #pragma unroll
    for (int k=0;k<32;k++){
      v2f aa = a2[k];
      v2f ph = aa * C2;                                              // pk_mul
      v2f fma0 = __builtin_elementwise_fma(aa, C2, -ph);             // pk_fma
      v2f pl = __builtin_elementwise_fma(aa, CC2, fma0);             // pk_fma
      v2f e; e[0] = __builtin_rintf(ph[0]); e[1] = __builtin_rintf(ph[1]); // v_rndne
      v2f ar = (ph - e) + pl;                                        // pk_sub, pk_add (no contract)
      float r0 = __builtin_ldexpf(exp2_raw(ar[0]), (int)e[0]);       // v_exp, v_cvt, v_ldexp
      float r1 = __builtin_ldexpf(exp2_raw(ar[1]), (int)e[1]);
      v2f ev; ev[0] = r0; ev[1] = r1;
      v2f t = ev * wv2[k];                                           // pk_mul
      y = y + t[0];
      y = y + t[1];
    }
    yraw[blk*900 + p] = y;
    acc1 += (double)y;
    acc2 += (double)y * (double)y;
  }
  #pragma unroll
  for (int off=32; off>0; off>>=1){
    acc1 += __shfl_down(acc1, off);
    acc2 += __shfl_down(acc2, off);
  }
  __shared__ double sh1[4], sh2[4];
  int wid = threadIdx.x >> 6;
  if ((threadIdx.x & 63) == 0){ sh1[wid] = acc1; sh2[wid] = acc2; }
  __syncthreads();
  if (threadIdx.x == 0){
    atomicAdd(&S1[d], sh1[0]+sh1[1]+sh1[2]+sh1[3]);
    atomicAdd(&S2[d], sh2[0]+sh2[1]+sh2[2]+sh2[3]);
  }
}

// ================= XLA f32 erfinv (Giles) =================
__device__ __forceinline__ float erfinv_xla(float x){
#pragma clang fp contract(off)
  float w = -log1pf(-(x*x));
  float p;
  if (w < 5.0f){
    w = w - 2.5f;
    p = 2.81022636e-08f;
    p = 3.43273939e-07f  + p*w;
    p = -3.5233877e-06f  + p*w;
    p = -4.39150654e-06f + p*w;
    p = 0.00021858087f   + p*w;
    p = -0.00125372503f  + p*w;
    p = -0.00417768164f  + p*w;
    p = 0.246640727f     + p*w;
    p = 1.50140941f      + p*w;
  } else {
    w = sqrtf(w) - 3.0f;
    p = -0.000200214257f;
    p = 0.000100950558f  + p*w;
    p = 0.00134934322f   + p*w;
    p = -0.00367342844f  + p*w;
    p = 0.00573950773f   + p*w;
    p = -0.0076224613f   + p*w;
    p = 0.00943887047f   + p*w;
    p = 1.00167406f      + p*w;
    p = 2.83297682f      + p*w;
  }
  return p * x;
}

// ================= XLA/Eigen fast tanh f32 =================
__device__ __forceinline__ float fast_tanh_xla(float x){
  float ax = fabsf(x);
  float cx = fmaxf(fminf(x, 7.90531110763549805f), -7.90531110763549805f);
  float x2 = cx*cx;
  float np_ = fmaf(x2, -2.76076847742355e-16f, 2.00018790482477e-13f);
  np_ = fmaf(x2, np_, -8.60467152213735e-11f);
  np_ = fmaf(x2, np_, 5.12229709037114e-08f);
  np_ = fmaf(x2, np_, 1.48572235717979e-05f);
  np_ = fmaf(x2, np_, 6.37261928875436e-04f);
  np_ = fmaf(x2, np_, 4.89352455891786e-03f);
  float num = cx * np_;
  float dp_ = fmaf(x2, 1.19825839466702e-06f, 1.18534705686654e-04f);
  dp_ = fmaf(x2, dp_, 2.26843463243900e-03f);
  dp_ = fmaf(x2, dp_, 4.89352518554385e-03f);
  return (ax < 0.0004f) ? x : (num / dp_);
}

// ================= BN finalize + normalize + noise + stochastic quant =================
__global__ __launch_bounds__(256) void c3_k(float* __restrict__ out,
    const double* __restrict__ S1, const double* __restrict__ S2){
#pragma clang fp contract(off)
  const int base = blockIdx.x * 256;
  // <=2 distinct channels per 256-block: finalize mean/var once (exact same math)
  __shared__ float smv[4];
  const int dA = (base / 900) & 127;
  const int dB = ((base + 255) / 900) & 127;
  if (threadIdx.x < 2){
    int dd = threadIdx.x ? dB : dA;
    double m = S1[dd] / 14400.0;
    float m32 = (float)m;
    double ey2 = S2[dd] / 14400.0;
    double v = ey2 - 2.0*(double)m32*m + (double)m32*(double)m32;
    smv[threadIdx.x*2+0] = m32;
    smv[threadIdx.x*2+1] = (float)v;
  }
  __syncthreads();
  const int i = base + threadIdx.x;   // NELEM = 7200*256 exactly, no tail
  const int d = (i / 900) & 127;
  const int sb = (d != dA) ? 2 : 0;
  const float m32 = smv[sb], var32 = smv[sb+1];

  float yr = out[NELEM + i];
  float y = (yr - m32) / sqrtf(var32 + 1e-5f);

  { uint32_t x0 = 0u, x1 = (uint32_t)i; tf2x32(NK.a, NK.b, x0, x1);
    uint32_t nb = x0 ^ x1;
    float u01 = __uint_as_float((nb >> 9) | 0x3f800000u) - 1.0f;
    const float lo = __uint_as_float(0xBF7FFFFFu);
    float un = u01 * 2.0f + lo;
    un = fmaxf(lo, un);
    float noise = __uint_as_float(0x3FB504F3u) * erfinv_xla(un);
    y = y + noise * 0.2f;
  }
  out[i] = y;

  uint32_t x0 = 0u, x1 = (uint32_t)i;
  tf2x32(UK.a, UK.b, x0, x1);
  uint32_t rb = x0 ^ x1;
  float r = __uint_as_float((rb >> 9) | 0x3f800000u) - 1.0f;

  float s = 0.5f + 0.5f * fast_tanh_xla(0.5f * y);
  out[NELEM + i] = (s > r) ? 1.0f : 0.0f;
}

extern "C" void kernel_launch(void* const* d_in, const int* in_sizes, int n_in,
                              void* d_out, int out_size, void* d_ws, size_t ws_size,
                              hipStream_t stream) {
  (void)in_sizes; (void)n_in; (void)out_size;
  const float* inp = (const float*)d_in[0];
  const float* ck  = (const float*)d_in[1];
  const float* lut = (const float*)d_in[2];
  float* out = (float*)d_out;

  uint32_t* sel = (uint32_t*)d_ws;                   // 768 u32
  double*   S1  = (double*)((char*)d_ws + 4096);     // 128
  double*   S2  = S1 + 128;                          // 128 (contiguous with S1)
  v2f*      lg  = (v2f*)((char*)d_ws + 8192);        // NPIX float2 = 8 MiB

  const size_t ws_need = 8192 + (size_t)NPIX * 8;

  hipLaunchKernelGGL(argmax_k, dim3(768),  dim3(64),  0, stream, ck, sel, S1);
  if (ws_size >= ws_need){
    hipLaunchKernelGGL(pre_k,   dim3(NPIX/256), dim3(256), 0, stream, inp, lg);
    hipLaunchKernelGGL(c1_k<1>, dim3(2048),     dim3(256), 0, stream, inp, lg, lut, sel, out + NELEM, S1, S2);
  } else {
    hipLaunchKernelGGL(c1_k<0>, dim3(2048),     dim3(256), 0, stream, inp, lg, lut, sel, out + NELEM, S1, S2);
  }
  hipLaunchKernelGGL(c3_k, dim3(7200), dim3(256), 0, stream, out, S1, S2);
}